// Round 4
// baseline (1233.996 us; speedup 1.0000x reference)
//
#include <hip/hip_runtime.h>

// Problem: x (32,512,512) fp32 -> pad 128 each side -> (32,768,768)
//          -> nearest-neighbor x4 upsample -> out (32,3072,3072) fp32.
// Interior of output (nonzero) is rows/cols [512, 2560); bounds % 4 == 0, so
// every aligned float4 of an output row is either all-zero padding or a
// 4-wide broadcast of one input element:
//   out[b][i][4*jq..4*jq+3] = x[b][(i-512)>>2][jq-128]  for jq in [128,640)
//
// R3 lesson: one-row-per-block (98304 short-lived WGs, 3 stores/thread) ran at
// ~2.9 TB/s while the harness fill kernel (few long-lived grid-stride blocks)
// hits 6.27 TB/s on the same buffer. Per-WG overhead + too few outstanding
// stores. Fix: 2048 blocks, each looping 48 consecutive rows (576 KB/block).

typedef float vfloat4 __attribute__((ext_vector_type(4)));

constexpr int OUTW   = 3072;   // output width/height
constexpr int IN     = 512;
constexpr int Q_LO   = 128;    // first interior quad-col (512/4)
constexpr int Q_HI   = 640;    // one-past-last interior quad-col (2560/4)
constexpr int ROW_LO = 512;    // first interior output row
constexpr int ROW_HI = 2560;   // one-past-last interior output row
constexpr int ROWS_PER_BLOCK = 48;   // 64 blocks cover 3072 rows

__global__ __launch_bounds__(256) void scale_layer_kernel(
    const float* __restrict__ x, float* __restrict__ out) {
    const int b  = blockIdx.y;                    // batch, 0..31
    const int i0 = blockIdx.x * ROWS_PER_BLOCK;   // first output row
    const int t  = (int)threadIdx.x;

    const float* __restrict__ img = x + (size_t)b * IN * IN;
    float* __restrict__ obase = out + (size_t)b * OUTW * OUTW;

    for (int r = 0; r < ROWS_PER_BLOCK; ++r) {
        const int i = i0 + r;                     // output row, 0..3071
        vfloat4* __restrict__ orow =
            reinterpret_cast<vfloat4*>(obase + (size_t)i * OUTW);

        const bool in_row = (i >= ROW_LO) && (i < ROW_HI);
        // Only dereferenced when in_row; 4 consecutive i share one input row,
        // so these reads are L1-hot within the block.
        const float* irow = img + (size_t)((i - ROW_LO) >> 2) * IN;

        #pragma unroll
        for (int k = 0; k < 3; ++k) {
            const int jq = t + k * 256;           // quad-column 0..767
            float v = 0.0f;
            if (in_row && jq >= Q_LO && jq < Q_HI) {
                v = irow[jq - Q_LO];              // coalesced 4B/lane
            }
            vfloat4 vv = {v, v, v, v};
            orow[jq] = vv;                        // global_store_dwordx4
        }
    }
}

extern "C" void kernel_launch(void* const* d_in, const int* in_sizes, int n_in,
                              void* d_out, int out_size, void* d_ws, size_t ws_size,
                              hipStream_t stream) {
    const float* x = (const float*)d_in[0];
    float* out = (float*)d_out;
    dim3 grid(OUTW / ROWS_PER_BLOCK, 32);   // 64 x 32 = 2048 blocks (8/CU)
    scale_layer_kernel<<<grid, 256, 0, stream>>>(x, out);
}

// Round 5
// 1192.708 us; speedup vs baseline: 1.0346x; 1.0346x over previous
//
#include <hip/hip_runtime.h>

// Problem: x (32,512,512) fp32 -> pad 128 each side -> (32,768,768)
//          -> nearest-neighbor x4 upsample -> out (32,3072,3072) fp32.
// Interior of output is rows [512,2560) x cols [512,2560). Every aligned
// float4 of an output row is either all-zero padding or a 4-wide broadcast of
// one input element.
//
// R4 lesson: dur_us ~1200 is dominated by the harness's 4.83 GB 0xAA poison
// fill (~770 us) inside the timed loop; our kernel is <769 us (absent from
// top-5). This round: purify the write streams — padding regions are written
// by dedicated zero-fill code paths (no loads, no predicates, linear), and
// the interior amortizes each input load over 4 output rows (2 loads -> 8
// coalesced broadcast stores). One launch; blockIdx.z = region.

typedef float vfloat4 __attribute__((ext_vector_type(4)));

constexpr int OUTW = 3072;           // output width/height (floats)
constexpr int QW   = OUTW / 4;       // 768 quads per output row
constexpr int IN   = 512;
constexpr int GX   = 64;             // blocks in x per (z, batch)
constexpr int NTHR = 256;

// Region sizes in quads (per image):
//   top    rows [0,512)    : 512*768  = 393216 quads (contiguous)
//   bottom rows [2560,3072): 512*768  = 393216 quads (contiguous)
//   sides  rows [512,2560) : 2048 rows * (128 left + 128 right) = 524288
//   interior               : 2048 rows * 512 quads (written by z=3)
constexpr int TOPQ  = 512 * QW;
constexpr int SIDEQ = 2048 * 256;

__global__ __launch_bounds__(NTHR) void scale_layer_kernel(
    const float* __restrict__ x, float* __restrict__ out) {
    const int b = blockIdx.y;        // batch 0..31
    const int z = blockIdx.z;        // region 0..3
    const int t = (int)(blockIdx.x * NTHR + threadIdx.x);
    const int stride = GX * NTHR;    // 16384

    float* __restrict__ obase = out + (size_t)b * OUTW * OUTW;
    vfloat4* __restrict__ oq = reinterpret_cast<vfloat4*>(obase);
    const vfloat4 zero = {0.f, 0.f, 0.f, 0.f};

    if (z == 0) {                    // top pad: linear zero stream
        for (int idx = t; idx < TOPQ; idx += stride) oq[idx] = zero;
    } else if (z == 1) {             // bottom pad: linear zero stream
        vfloat4* p = oq + (size_t)2560 * QW;
        for (int idx = t; idx < TOPQ; idx += stride) p[idx] = zero;
    } else if (z == 2) {             // left/right bands of middle rows
        for (int idx = t; idx < SIDEQ; idx += stride) {
            const int row = idx >> 8;          // 0..2047
            const int q   = idx & 255;         // 0..255
            const int jq  = q + (q >= 128 ? 512 : 0);  // [0,128) or [640,768)
            oq[(size_t)(512 + row) * QW + jq] = zero;
        }
    } else {                         // interior: broadcast upsample
        const int r0 = (int)blockIdx.x * 8;    // 8 input rows per block
        const int tt = (int)threadIdx.x;
        const float* __restrict__ img = x + (size_t)b * IN * IN;
        for (int r = r0; r < r0 + 8; ++r) {
            const float v0 = img[(size_t)r * IN + tt];        // coalesced
            const float v1 = img[(size_t)r * IN + tt + 256];  // coalesced
            const vfloat4 a = {v0, v0, v0, v0};
            const vfloat4 c = {v1, v1, v1, v1};
            const int i0 = 512 + r * 4;
            #pragma unroll
            for (int rr = 0; rr < 4; ++rr) {
                vfloat4* orow = oq + (size_t)(i0 + rr) * QW;
                orow[128 + tt] = a;   // quads [128,384) — 1 KiB/wave contiguous
                orow[384 + tt] = c;   // quads [384,640)
            }
        }
    }
}

extern "C" void kernel_launch(void* const* d_in, const int* in_sizes, int n_in,
                              void* d_out, int out_size, void* d_ws, size_t ws_size,
                              hipStream_t stream) {
    const float* x = (const float*)d_in[0];
    float* out = (float*)d_out;
    dim3 grid(GX, 32, 4);            // 8192 blocks; z = region
    scale_layer_kernel<<<grid, NTHR, 0, stream>>>(x, out);
}